// Round 1
// baseline (481.536 us; speedup 1.0000x reference)
//
#include <hip/hip_runtime.h>

typedef __bf16 bf16x8 __attribute__((ext_vector_type(8)));
typedef float floatx4 __attribute__((ext_vector_type(4)));
typedef unsigned short ushortx8 __attribute__((ext_vector_type(8)));
typedef unsigned short ushort_t;

#define NC      100000
#define NCP     100096      // 782*128
#define EMBD    512
#define BATCH   512
#define BM      128
#define BN      128
#define BK      32
#define NCH     782         // ceil(NC/BN)

#define COS_M   0.8775825618903728f
#define SIN_M   0.479425538604203f
#define THRESH  (-0.8775825618903728f)
#define MM_C    0.2397127693021015f

__device__ __forceinline__ ushort_t f2bf(float f) {
  __bf16 h = (__bf16)f;
  return __builtin_bit_cast(ushort_t, h);
}

#define GLOAD16(g, l) __builtin_amdgcn_global_load_lds( \
    (const __attribute__((address_space(1))) void*)(g), \
    (__attribute__((address_space(3))) void*)(l), 16, 0, 0)

// ---------------------------------------------------------------- detect int64
__global__ void detect64_k(const int* __restrict__ labels, int* __restrict__ flag) {
  __shared__ int nz;
  if (threadIdx.x == 0) nz = 0;
  __syncthreads();
  // If labels are int64, odd 32-bit words are all high-halves == 0 (labels in [0,1e5)).
  // If int32, words 1,3,...,511 are real labels; P(all zero) ~ 0.
  if (labels[2 * threadIdx.x + 1] != 0) atomicAdd(&nz, 1);
  __syncthreads();
  if (threadIdx.x == 0) flag[0] = (nz == 0) ? 1 : 0;
}

// ---------------------------------------------------------------- prep A (emb -> bf16, normalized iff margin branch)
__global__ __launch_bounds__(256) void prep_a_k(
    const float* __restrict__ emb, const int* __restrict__ epoch,
    ushort_t* __restrict__ Abf) {
  const bool mm = (*epoch > 30);
  const int w = threadIdx.x >> 6, lane = threadIdx.x & 63;
  const int row = blockIdx.x * 4 + w;            // grid 128 -> rows 0..511
  const float* src = emb + (size_t)row * EMBD + lane * 8;
  float4 a = *(const float4*)src;
  float4 b = *(const float4*)(src + 4);
  float ss = a.x*a.x + a.y*a.y + a.z*a.z + a.w*a.w
           + b.x*b.x + b.y*b.y + b.z*b.z + b.w*b.w;
  #pragma unroll
  for (int off = 32; off; off >>= 1) ss += __shfl_xor(ss, off, 64);
  const float inv = mm ? (1.0f / fmaxf(sqrtf(ss), 1e-12f)) : 1.0f;
  ushortx8 o;
  o[0] = f2bf(a.x*inv); o[1] = f2bf(a.y*inv); o[2] = f2bf(a.z*inv); o[3] = f2bf(a.w*inv);
  o[4] = f2bf(b.x*inv); o[5] = f2bf(b.y*inv); o[6] = f2bf(b.z*inv); o[7] = f2bf(b.w*inv);
  *(ushortx8*)(Abf + (size_t)row * EMBD + lane * 8) = o;
}

// ---------------------------------------------------------------- prep W (weight or fc_weight -> bf16, normalized iff margin)
__global__ __launch_bounds__(256) void prep_w_k(
    const float* __restrict__ weight, const float* __restrict__ fcw,
    const int* __restrict__ epoch, ushort_t* __restrict__ Wbf) {
  const bool mm = (*epoch > 30);
  const float* W = mm ? weight : fcw;
  const int w = threadIdx.x >> 6, lane = threadIdx.x & 63;
  const int row = blockIdx.x * 4 + w;            // grid 25024 -> rows 0..100095
  if (row >= NCP) return;
  ushort_t* dst = Wbf + (size_t)row * EMBD + lane * 8;
  if (row >= NC) {                               // pad rows: zeros
    ushortx8 z = (ushortx8)0;
    *(ushortx8*)dst = z;
    return;
  }
  const float* src = W + (size_t)row * EMBD + lane * 8;
  float4 a = *(const float4*)src;
  float4 b = *(const float4*)(src + 4);
  float ss = a.x*a.x + a.y*a.y + a.z*a.z + a.w*a.w
           + b.x*b.x + b.y*b.y + b.z*b.z + b.w*b.w;
  #pragma unroll
  for (int off = 32; off; off >>= 1) ss += __shfl_xor(ss, off, 64);
  const float inv = mm ? (1.0f / fmaxf(sqrtf(ss), 1e-12f)) : 1.0f;
  ushortx8 o;
  o[0] = f2bf(a.x*inv); o[1] = f2bf(a.y*inv); o[2] = f2bf(a.z*inv); o[3] = f2bf(a.w*inv);
  o[4] = f2bf(b.x*inv); o[5] = f2bf(b.y*inv); o[6] = f2bf(b.z*inv); o[7] = f2bf(b.w*inv);
  *(ushortx8*)dst = o;
}

// ---------------------------------------------------------------- target logit (fp32, exact) + arcface margin
__global__ __launch_bounds__(256) void target_k(
    const float* __restrict__ emb, const float* __restrict__ weight,
    const float* __restrict__ fcw, const int* __restrict__ labels,
    const int* __restrict__ epoch, const int* __restrict__ flag64,
    float* __restrict__ tsc) {
  const bool mm = (*epoch > 30);
  const float* W = mm ? weight : fcw;
  const int w = threadIdx.x >> 6, lane = threadIdx.x & 63;
  const int b = blockIdx.x * 4 + w;              // grid 128 -> rows 0..511
  const int lab = (*flag64) ? labels[2 * b] : labels[b];
  const float* er = emb + (size_t)b * EMBD + lane * 8;
  const float* wr = W + (size_t)lab * EMBD + lane * 8;
  float4 e0 = *(const float4*)er,       e1 = *(const float4*)(er + 4);
  float4 w0 = *(const float4*)wr,       w1 = *(const float4*)(wr + 4);
  float dot = e0.x*w0.x + e0.y*w0.y + e0.z*w0.z + e0.w*w0.w
            + e1.x*w1.x + e1.y*w1.y + e1.z*w1.z + e1.w*w1.w;
  float ssa = e0.x*e0.x + e0.y*e0.y + e0.z*e0.z + e0.w*e0.w
            + e1.x*e1.x + e1.y*e1.y + e1.z*e1.z + e1.w*e1.w;
  float ssw = w0.x*w0.x + w0.y*w0.y + w0.z*w0.z + w0.w*w0.w
            + w1.x*w1.x + w1.y*w1.y + w1.z*w1.z + w1.w*w1.w;
  #pragma unroll
  for (int off = 32; off; off >>= 1) {
    dot += __shfl_xor(dot, off, 64);
    ssa += __shfl_xor(ssa, off, 64);
    ssw += __shfl_xor(ssw, off, 64);
  }
  if (lane == 0) {
    if (mm) {
      float cosv = dot / (fmaxf(sqrtf(ssa), 1e-12f) * fmaxf(sqrtf(ssw), 1e-12f));
      float sinv = sqrtf(fmaxf(1.0f - cosv * cosv, 0.0f));
      float wmarg = cosv * COS_M - sinv * SIN_M;
      float nt = (cosv > THRESH) ? wmarg : (cosv - MM_C);
      tsc[b] = 64.0f * nt;
    } else {
      tsc[b] = dot;
    }
  }
}

// ---------------------------------------------------------------- fused GEMM + chunk-softmax partials
__global__ __launch_bounds__(256, 2) void gemm_fused_k(
    const ushort_t* __restrict__ Abf, const ushort_t* __restrict__ Wbf,
    const float* __restrict__ tsc, const int* __restrict__ labels,
    const int* __restrict__ flag64, const int* __restrict__ epoch,
    float2* __restrict__ partials) {
  const bool mm = (*epoch > 30);
  const float scale = mm ? 64.0f : 1.0f;

  __shared__ ushort_t As[BM * BK];   // 8 KB
  __shared__ ushort_t Bs[BN * BK];   // 8 KB
  __shared__ float redM[BM * 2];
  __shared__ float redS[BM * 2];
  __shared__ float tscS[BM];
  __shared__ int   labS[BM];

  const int tid  = threadIdx.x;
  const int lane = tid & 63;
  const int w    = tid >> 6;
  const int wm   = (w >> 1) * 64;
  const int wn   = (w & 1) * 64;
  const int bm   = blockIdx.x & 3;        // 4 M-tiles
  const int bn   = blockIdx.x >> 2;       // 782 N-chunks
  const int m0   = bm * BM;
  const int n0   = bn * BN;

  if (tid < BM) {
    tscS[tid] = tsc[m0 + tid];
    labS[tid] = (*flag64) ? labels[2 * (m0 + tid)] : labels[m0 + tid];
  }

  floatx4 acc[4][4];
  #pragma unroll
  for (int i = 0; i < 4; i++)
    #pragma unroll
    for (int j = 0; j < 4; j++) acc[i][j] = (floatx4){0.f, 0.f, 0.f, 0.f};

  // staging addresses: 8 segments of 1KB per tile; wave w does segs {2w,2w+1}
  const int seg0 = 2 * w, seg1 = 2 * w + 1;
  const int r_in = lane >> 2;             // 0..15 row within segment
  const int k_in = (lane & 3) * 8;        // 0,8,16,24
  const ushort_t* gA0 = Abf + (size_t)(m0 + seg0 * 16 + r_in) * EMBD + k_in;
  const ushort_t* gA1 = Abf + (size_t)(m0 + seg1 * 16 + r_in) * EMBD + k_in;
  const ushort_t* gB0 = Wbf + (size_t)(n0 + seg0 * 16 + r_in) * EMBD + k_in;
  const ushort_t* gB1 = Wbf + (size_t)(n0 + seg1 * 16 + r_in) * EMBD + k_in;
  ushort_t* lA0 = &As[seg0 * 512 + lane * 8];
  ushort_t* lA1 = &As[seg1 * 512 + lane * 8];
  ushort_t* lB0 = &Bs[seg0 * 512 + lane * 8];
  ushort_t* lB1 = &Bs[seg1 * 512 + lane * 8];

  const int koff = (lane >> 4) * 8;
  const int rsel = lane & 15;

  for (int kt = 0; kt < EMBD / BK; ++kt) {
    GLOAD16(gA0 + kt * BK, lA0);
    GLOAD16(gA1 + kt * BK, lA1);
    GLOAD16(gB0 + kt * BK, lB0);
    GLOAD16(gB1 + kt * BK, lB1);
    __syncthreads();

    bf16x8 af[4], bfv[4];
    #pragma unroll
    for (int mi = 0; mi < 4; mi++)
      af[mi] = *(const bf16x8*)&As[(wm + mi * 16 + rsel) * BK + koff];
    #pragma unroll
    for (int ni = 0; ni < 4; ni++)
      bfv[ni] = *(const bf16x8*)&Bs[(wn + ni * 16 + rsel) * BK + koff];
    #pragma unroll
    for (int mi = 0; mi < 4; mi++)
      #pragma unroll
      for (int ni = 0; ni < 4; ni++)
        acc[mi][ni] = __builtin_amdgcn_mfma_f32_16x16x32_bf16(
            af[mi], bfv[ni], acc[mi][ni], 0, 0, 0);
    __syncthreads();
  }

  // epilogue: per-row (max, sumexp) over this block's 128 columns.
  // C/D layout: col = lane&15 (N), row = (lane>>4)*4 + r (M).
  const int colq = lane & 15;
  const int rowq = lane >> 4;
  #pragma unroll
  for (int mi = 0; mi < 4; mi++) {
    #pragma unroll
    for (int r = 0; r < 4; r++) {
      const int rl = wm + mi * 16 + rowq * 4 + r;   // row within block
      const int lab = labS[rl];
      const float tv = tscS[rl];
      float v[4];
      #pragma unroll
      for (int ni = 0; ni < 4; ni++) {
        const int cg = n0 + wn + ni * 16 + colq;    // global class
        float x = acc[mi][ni][r] * scale;
        if (cg >= NC) x = -1e30f;
        else if (cg == lab) x = tv;                 // substitute margin target
        v[ni] = x;
      }
      float mx = fmaxf(fmaxf(v[0], v[1]), fmaxf(v[2], v[3]));
      #pragma unroll
      for (int off = 1; off < 16; off <<= 1) mx = fmaxf(mx, __shfl_xor(mx, off, 64));
      float s = __expf(v[0] - mx) + __expf(v[1] - mx)
              + __expf(v[2] - mx) + __expf(v[3] - mx);
      #pragma unroll
      for (int off = 1; off < 16; off <<= 1) s += __shfl_xor(s, off, 64);
      if (colq == 0) { redM[rl * 2 + (w & 1)] = mx; redS[rl * 2 + (w & 1)] = s; }
    }
  }
  __syncthreads();
  if (tid < BM) {
    const float ma = redM[tid * 2], mb = redM[tid * 2 + 1];
    const float sa = redS[tid * 2], sb = redS[tid * 2 + 1];
    const float M = fmaxf(ma, mb);
    const float S = sa * __expf(ma - M) + sb * __expf(mb - M);
    partials[(size_t)(m0 + tid) * NCH + bn] = make_float2(M, S);
  }
}

// ---------------------------------------------------------------- per-row logsumexp merge
__global__ __launch_bounds__(256) void rowmerge_k(
    const float2* __restrict__ partials, const float* __restrict__ tsc,
    float* __restrict__ loss_row) {
  const int row = blockIdx.x;    // 512
  const int tid = threadIdx.x;   // 256
  float M = -1e30f, S = 0.0f;
  for (int j = tid; j < NCH; j += 256) {
    const float2 p = partials[(size_t)row * NCH + j];
    if (p.x > M) { S = S * __expf(M - p.x) + p.y; M = p.x; }
    else         { S += p.y * __expf(p.x - M); }
  }
  __shared__ float sm[256], sv[256];
  sm[tid] = M; sv[tid] = S;
  __syncthreads();
  for (int st = 128; st > 0; st >>= 1) {
    if (tid < st) {
      const float m2 = sm[tid + st], s2 = sv[tid + st];
      const float m1 = sm[tid],      s1 = sv[tid];
      const float Mn = fmaxf(m1, m2);
      sv[tid] = s1 * __expf(m1 - Mn) + s2 * __expf(m2 - Mn);
      sm[tid] = Mn;
    }
    __syncthreads();
  }
  if (tid == 0) loss_row[row] = (sm[0] + __logf(sv[0])) - tsc[row];
}

// ---------------------------------------------------------------- final mean
__global__ __launch_bounds__(512) void finalsum_k(
    const float* __restrict__ loss_row, float* __restrict__ out) {
  const int tid = threadIdx.x;   // 512
  __shared__ float buf[512];
  buf[tid] = loss_row[tid];
  __syncthreads();
  for (int st = 256; st > 0; st >>= 1) {
    if (tid < st) buf[tid] += buf[tid + st];
    __syncthreads();
  }
  if (tid == 0) out[0] = buf[0] / 512.0f;
}

// ----------------------------------------------------------------
extern "C" void kernel_launch(void* const* d_in, const int* in_sizes, int n_in,
                              void* d_out, int out_size, void* d_ws, size_t ws_size,
                              hipStream_t stream) {
  const float* emb    = (const float*)d_in[0];
  const float* weight = (const float*)d_in[1];
  const float* fcw    = (const float*)d_in[2];
  const int*   labels = (const int*)d_in[3];
  const int*   epoch  = (const int*)d_in[4];
  float* out = (float*)d_out;

  char* ws = (char*)d_ws;
  size_t off = 0;
  ushort_t* Abf = (ushort_t*)(ws + off); off += (size_t)BATCH * EMBD * 2;       // 512 KB
  ushort_t* Wbf = (ushort_t*)(ws + off); off += (size_t)NCP * EMBD * 2;         // ~97.8 MB
  float* tsc       = (float*)(ws + off); off += BATCH * 4;
  float2* partials = (float2*)(ws + off); off += (size_t)BATCH * NCH * 8;       // ~3.2 MB
  float* loss_row  = (float*)(ws + off); off += BATCH * 4;
  int* flag64      = (int*)(ws + off);   off += 256;

  detect64_k<<<1, 256, 0, stream>>>(labels, flag64);
  prep_a_k <<<BATCH / 4, 256, 0, stream>>>(emb, epoch, Abf);
  prep_w_k <<<NCP / 4, 256, 0, stream>>>(weight, fcw, epoch, Wbf);
  target_k <<<BATCH / 4, 256, 0, stream>>>(emb, weight, fcw, labels, epoch, flag64, tsc);
  gemm_fused_k<<<4 * NCH, 256, 0, stream>>>(Abf, Wbf, tsc, labels, flag64, epoch, partials);
  rowmerge_k<<<BATCH, 256, 0, stream>>>(partials, tsc, loss_row);
  finalsum_k<<<1, 512, 0, stream>>>(loss_row, out);
}

// Round 2
// 473.496 us; speedup vs baseline: 1.0170x; 1.0170x over previous
//
#include <hip/hip_runtime.h>

typedef __bf16 bf16x8 __attribute__((ext_vector_type(8)));
typedef float floatx4 __attribute__((ext_vector_type(4)));
typedef unsigned short ushortx8 __attribute__((ext_vector_type(8)));
typedef unsigned short ushort_t;

#define NC      100000
#define NCP     100096      // 782*128
#define EMBD    512
#define BATCH   512
#define BM      256
#define BN      128
#define BK      32
#define NCH     782         // ceil(NC/BN)

#define COS_M   0.8775825618903728f
#define SIN_M   0.479425538604203f
#define THRESH  (-0.8775825618903728f)
#define MM_C    0.2397127693021015f

__device__ __forceinline__ ushort_t f2bf(float f) {
  __bf16 h = (__bf16)f;
  return __builtin_bit_cast(ushort_t, h);
}

#define GLOAD16(g, l) __builtin_amdgcn_global_load_lds( \
    (const __attribute__((address_space(1))) void*)(g), \
    (__attribute__((address_space(3))) void*)(l), 16, 0, 0)

// ---------------------------------------------------------------- prep_small
// Fuses: int64-label detect, label decode, emb->bf16 (normalized iff margin),
// exact fp32 target logit + arcface margin, out[0]=0 init for atomic finish.
// grid 128 x 256: block handles 4 batch rows (one per wave).
__global__ __launch_bounds__(256) void prep_small_k(
    const float* __restrict__ emb, const float* __restrict__ weight,
    const float* __restrict__ fcw, const int* __restrict__ labels,
    const int* __restrict__ epoch, ushort_t* __restrict__ Abf,
    float* __restrict__ tsc, int* __restrict__ lab32,
    float* __restrict__ out) {
  const bool mm = (*epoch > 30);
  const int tid = threadIdx.x;
  // int64 detect: if labels are int64, all odd 32-bit words (high halves) are 0.
  const int pred = (labels[2 * tid + 1] != 0) ? 1 : 0;
  const bool is64 = (__syncthreads_or(pred) == 0);

  const int w = tid >> 6, lane = tid & 63;
  const int row = blockIdx.x * 4 + w;            // 0..511
  const int lab = is64 ? labels[2 * row] : labels[row];
  const float* W = mm ? weight : fcw;

  const float* er = emb + (size_t)row * EMBD + lane * 8;
  const float* wr = W + (size_t)lab * EMBD + lane * 8;
  float4 e0 = *(const float4*)er,  e1 = *(const float4*)(er + 4);
  float4 w0 = *(const float4*)wr,  w1 = *(const float4*)(wr + 4);
  float dot = e0.x*w0.x + e0.y*w0.y + e0.z*w0.z + e0.w*w0.w
            + e1.x*w1.x + e1.y*w1.y + e1.z*w1.z + e1.w*w1.w;
  float ssa = e0.x*e0.x + e0.y*e0.y + e0.z*e0.z + e0.w*e0.w
            + e1.x*e1.x + e1.y*e1.y + e1.z*e1.z + e1.w*e1.w;
  float ssw = w0.x*w0.x + w0.y*w0.y + w0.z*w0.z + w0.w*w0.w
            + w1.x*w1.x + w1.y*w1.y + w1.z*w1.z + w1.w*w1.w;
  #pragma unroll
  for (int off = 32; off; off >>= 1) {
    dot += __shfl_xor(dot, off, 64);
    ssa += __shfl_xor(ssa, off, 64);
    ssw += __shfl_xor(ssw, off, 64);
  }
  const float inva = mm ? (1.0f / fmaxf(sqrtf(ssa), 1e-12f)) : 1.0f;
  ushortx8 o;
  o[0] = f2bf(e0.x*inva); o[1] = f2bf(e0.y*inva); o[2] = f2bf(e0.z*inva); o[3] = f2bf(e0.w*inva);
  o[4] = f2bf(e1.x*inva); o[5] = f2bf(e1.y*inva); o[6] = f2bf(e1.z*inva); o[7] = f2bf(e1.w*inva);
  *(ushortx8*)(Abf + (size_t)row * EMBD + lane * 8) = o;

  if (lane == 0) {
    lab32[row] = lab;
    float tv;
    if (mm) {
      float cosv = dot / (fmaxf(sqrtf(ssa), 1e-12f) * fmaxf(sqrtf(ssw), 1e-12f));
      float sinv = sqrtf(fmaxf(1.0f - cosv * cosv, 0.0f));
      float wmarg = cosv * COS_M - sinv * SIN_M;
      float nt = (cosv > THRESH) ? wmarg : (cosv - MM_C);
      tv = 64.0f * nt;
    } else {
      tv = dot;
    }
    tsc[row] = tv;
  }
  if (blockIdx.x == 0 && tid == 0) out[0] = 0.0f;
}

// ---------------------------------------------------------------- prep W
__global__ __launch_bounds__(256) void prep_w_k(
    const float* __restrict__ weight, const float* __restrict__ fcw,
    const int* __restrict__ epoch, ushort_t* __restrict__ Wbf) {
  const bool mm = (*epoch > 30);
  const float* W = mm ? weight : fcw;
  const int w = threadIdx.x >> 6, lane = threadIdx.x & 63;
  const int row = blockIdx.x * 4 + w;            // grid 25024 -> rows 0..100095
  ushort_t* dst = Wbf + (size_t)row * EMBD + lane * 8;
  if (row >= NC) {                               // pad rows: zeros
    *(ushortx8*)dst = (ushortx8)0;
    return;
  }
  const float* src = W + (size_t)row * EMBD + lane * 8;
  float4 a = *(const float4*)src;
  float4 b = *(const float4*)(src + 4);
  float ss = a.x*a.x + a.y*a.y + a.z*a.z + a.w*a.w
           + b.x*b.x + b.y*b.y + b.z*b.z + b.w*b.w;
  #pragma unroll
  for (int off = 32; off; off >>= 1) ss += __shfl_xor(ss, off, 64);
  const float inv = mm ? (1.0f / fmaxf(sqrtf(ss), 1e-12f)) : 1.0f;
  ushortx8 o;
  o[0] = f2bf(a.x*inv); o[1] = f2bf(a.y*inv); o[2] = f2bf(a.z*inv); o[3] = f2bf(a.w*inv);
  o[4] = f2bf(b.x*inv); o[5] = f2bf(b.y*inv); o[6] = f2bf(b.z*inv); o[7] = f2bf(b.w*inv);
  *(ushortx8*)dst = o;
}

// ---------------------------------------------------------------- fused GEMM + chunk-softmax
// block = 256x128 output (bm in {0,1}, bn in 0..781). Wave w owns rows
// [w*64, w*64+64) x all 128 cols: acc[4][8] frags. Swizzle puts the two
// bm-blocks of one bn 8 dispatch-ids apart (same XCD -> L2 reuse on Wbf).
__global__ __launch_bounds__(256, 2) void gemm_fused_k(
    const ushort_t* __restrict__ Abf, const ushort_t* __restrict__ Wbf,
    const float* __restrict__ tsc, const int* __restrict__ lab32,
    const int* __restrict__ epoch, float2* __restrict__ partials) {
  const int g = blockIdx.x >> 4, t = blockIdx.x & 15;
  const int bn = g * 8 + (t & 7);
  const int bm = t >> 3;
  if (bn >= NCH) return;

  const bool mm = (*epoch > 30);
  const float scale = mm ? 64.0f : 1.0f;

  __shared__ ushort_t As[BM * BK];   // 16 KB
  __shared__ ushort_t Bs[BN * BK];   // 8 KB
  __shared__ float tscS[BM];
  __shared__ int   labS[BM];

  const int tid  = threadIdx.x;
  const int lane = tid & 63;
  const int w    = tid >> 6;
  const int wm   = w * 64;
  const int m0   = bm * BM;
  const int n0   = bn * BN;

  tscS[tid] = tsc[m0 + tid];
  labS[tid] = lab32[m0 + tid];

  floatx4 acc[4][8];
  #pragma unroll
  for (int i = 0; i < 4; i++)
    #pragma unroll
    for (int j = 0; j < 8; j++) acc[i][j] = (floatx4){0.f, 0.f, 0.f, 0.f};

  // staging: A = 16 segs of 1KB (wave w: segs 4w..4w+3), B = 8 segs (wave w: 2w..2w+1)
  const int r_in = lane >> 2;             // row within 16-row segment
  const int k_in = (lane & 3) * 8;
  const ushort_t* gA[4];
  ushort_t* lA[4];
  #pragma unroll
  for (int s = 0; s < 4; s++) {
    gA[s] = Abf + (size_t)(m0 + wm + s * 16 + r_in) * EMBD + k_in;
    lA[s] = &As[(wm + s * 16) * BK + lane * 8];
  }
  const ushort_t* gB[2];
  ushort_t* lB[2];
  #pragma unroll
  for (int s = 0; s < 2; s++) {
    gB[s] = Wbf + (size_t)(n0 + w * 32 + s * 16 + r_in) * EMBD + k_in;
    lB[s] = &Bs[(w * 32 + s * 16) * BK + lane * 8];
  }

  const int koff = (lane >> 4) * 8;
  const int rsel = lane & 15;

  for (int kt = 0; kt < EMBD / BK; ++kt) {
    #pragma unroll
    for (int s = 0; s < 4; s++) GLOAD16(gA[s] + kt * BK, lA[s]);
    #pragma unroll
    for (int s = 0; s < 2; s++) GLOAD16(gB[s] + kt * BK, lB[s]);
    __syncthreads();

    bf16x8 af[4], bv[8];
    #pragma unroll
    for (int mi = 0; mi < 4; mi++)
      af[mi] = *(const bf16x8*)&As[(wm + mi * 16 + rsel) * BK + koff];
    #pragma unroll
    for (int ni = 0; ni < 8; ni++)
      bv[ni] = *(const bf16x8*)&Bs[(ni * 16 + rsel) * BK + koff];
    #pragma unroll
    for (int mi = 0; mi < 4; mi++)
      #pragma unroll
      for (int ni = 0; ni < 8; ni++)
        acc[mi][ni] = __builtin_amdgcn_mfma_f32_16x16x32_bf16(
            af[mi], bv[ni], acc[mi][ni], 0, 0, 0);
    __syncthreads();
  }

  // epilogue: rows are wave-exclusive; 128-col (max, sumexp) entirely in-wave.
  // C/D layout: col = lane&15, row = (lane>>4)*4 + r.
  const int colq = lane & 15;
  const int rowq = lane >> 4;
  #pragma unroll
  for (int mi = 0; mi < 4; mi++) {
    #pragma unroll
    for (int r = 0; r < 4; r++) {
      const int rl = wm + mi * 16 + rowq * 4 + r;
      const int lab = labS[rl];
      const float tv = tscS[rl];
      float v[8];
      #pragma unroll
      for (int ni = 0; ni < 8; ni++) {
        const int cg = n0 + ni * 16 + colq;
        float x = acc[mi][ni][r] * scale;
        if (cg >= NC) x = -1e30f;
        else if (cg == lab) x = tv;
        v[ni] = x;
      }
      float mx = v[0];
      #pragma unroll
      for (int ni = 1; ni < 8; ni++) mx = fmaxf(mx, v[ni]);
      #pragma unroll
      for (int off = 1; off < 16; off <<= 1) mx = fmaxf(mx, __shfl_xor(mx, off, 64));
      float s = 0.0f;
      #pragma unroll
      for (int ni = 0; ni < 8; ni++) s += __expf(v[ni] - mx);
      #pragma unroll
      for (int off = 1; off < 16; off <<= 1) s += __shfl_xor(s, off, 64);
      if (colq == 0)
        partials[(size_t)(m0 + rl) * NCH + bn] = make_float2(mx, s);
    }
  }
}

// ---------------------------------------------------------------- per-row logsumexp + atomic mean
__global__ __launch_bounds__(256) void rowmerge_k(
    const float2* __restrict__ partials, const float* __restrict__ tsc,
    float* __restrict__ out) {
  const int row = blockIdx.x;    // 512
  const int tid = threadIdx.x;   // 256
  float M = -1e30f, S = 0.0f;
  for (int j = tid; j < NCH; j += 256) {
    const float2 p = partials[(size_t)row * NCH + j];
    if (p.x > M) { S = S * __expf(M - p.x) + p.y; M = p.x; }
    else         { S += p.y * __expf(p.x - M); }
  }
  __shared__ float sm[256], sv[256];
  sm[tid] = M; sv[tid] = S;
  __syncthreads();
  for (int st = 128; st > 0; st >>= 1) {
    if (tid < st) {
      const float m2 = sm[tid + st], s2 = sv[tid + st];
      const float m1 = sm[tid],      s1 = sv[tid];
      const float Mn = fmaxf(m1, m2);
      sv[tid] = s1 * __expf(m1 - Mn) + s2 * __expf(m2 - Mn);
      sm[tid] = Mn;
    }
    __syncthreads();
  }
  if (tid == 0) {
    const float loss = (sm[0] + __logf(sv[0])) - tsc[row];
    atomicAdd(out, loss * (1.0f / 512.0f));
  }
}

// ----------------------------------------------------------------
extern "C" void kernel_launch(void* const* d_in, const int* in_sizes, int n_in,
                              void* d_out, int out_size, void* d_ws, size_t ws_size,
                              hipStream_t stream) {
  const float* emb    = (const float*)d_in[0];
  const float* weight = (const float*)d_in[1];
  const float* fcw    = (const float*)d_in[2];
  const int*   labels = (const int*)d_in[3];
  const int*   epoch  = (const int*)d_in[4];
  float* out = (float*)d_out;

  char* ws = (char*)d_ws;
  size_t off = 0;
  ushort_t* Abf = (ushort_t*)(ws + off); off += (size_t)BATCH * EMBD * 2;
  ushort_t* Wbf = (ushort_t*)(ws + off); off += (size_t)NCP * EMBD * 2;
  float* tsc       = (float*)(ws + off); off += BATCH * 4;
  int* lab32       = (int*)(ws + off);   off += BATCH * 4;
  float2* partials = (float2*)(ws + off); off += (size_t)BATCH * NCH * 8;

  prep_small_k<<<BATCH / 4, 256, 0, stream>>>(emb, weight, fcw, labels, epoch,
                                              Abf, tsc, lab32, out);
  prep_w_k<<<NCP / 4, 256, 0, stream>>>(weight, fcw, epoch, Wbf);
  gemm_fused_k<<<98 * 16, 256, 0, stream>>>(Abf, Wbf, tsc, lab32, epoch, partials);
  rowmerge_k<<<BATCH, 256, 0, stream>>>(partials, tsc, out);
}

// Round 3
// 471.704 us; speedup vs baseline: 1.0208x; 1.0038x over previous
//
#include <hip/hip_runtime.h>

typedef float floatx4 __attribute__((ext_vector_type(4)));
typedef int   intx4   __attribute__((ext_vector_type(4)));
typedef int   intx8   __attribute__((ext_vector_type(8)));

#define NC      100000
#define NCP     100096      // 782*128
#define EMBD    512
#define BATCH   512
#define NCH     782         // ceil(NC/128)

#define COS_M   0.8775825618903728f
#define SIN_M   0.479425538604203f
#define THRESH  (-0.8775825618903728f)
#define MM_C    0.2397127693021015f

#define GLOAD16(g, l) __builtin_amdgcn_global_load_lds( \
    (const __attribute__((address_space(1))) void*)(g), \
    (__attribute__((address_space(3))) void*)(l), 16, 0, 0)

// pack 8 floats -> 8 fp8 e4m3 bytes (two dwords)
__device__ __forceinline__ uint2 pack8_fp8(float4 a, float4 b) {
  int lo = 0, hi = 0;
  lo = __builtin_amdgcn_cvt_pk_fp8_f32(a.x, a.y, lo, false);
  lo = __builtin_amdgcn_cvt_pk_fp8_f32(a.z, a.w, lo, true);
  hi = __builtin_amdgcn_cvt_pk_fp8_f32(b.x, b.y, hi, false);
  hi = __builtin_amdgcn_cvt_pk_fp8_f32(b.z, b.w, hi, true);
  return make_uint2((unsigned)lo, (unsigned)hi);
}

// ---------------------------------------------------------------- prep_small
// Fuses: int64-label detect, label decode, emb->fp8 (normalized iff margin),
// exact fp32 target logit + arcface margin, out[0]=0 init.
__global__ __launch_bounds__(256) void prep_small_k(
    const float* __restrict__ emb, const float* __restrict__ weight,
    const float* __restrict__ fcw, const int* __restrict__ labels,
    const int* __restrict__ epoch, unsigned char* __restrict__ Aq,
    float* __restrict__ tsc, int* __restrict__ lab32,
    float* __restrict__ out) {
  const bool mm = (*epoch > 30);
  const int tid = threadIdx.x;
  const int pred = (labels[2 * tid + 1] != 0) ? 1 : 0;
  const bool is64 = (__syncthreads_or(pred) == 0);

  const int w = tid >> 6, lane = tid & 63;
  const int row = blockIdx.x * 4 + w;            // 0..511
  const int lab = is64 ? labels[2 * row] : labels[row];
  const float* W = mm ? weight : fcw;

  const float* er = emb + (size_t)row * EMBD + lane * 8;
  const float* wr = W + (size_t)lab * EMBD + lane * 8;
  float4 e0 = *(const float4*)er,  e1 = *(const float4*)(er + 4);
  float4 w0 = *(const float4*)wr,  w1 = *(const float4*)(wr + 4);
  float dot = e0.x*w0.x + e0.y*w0.y + e0.z*w0.z + e0.w*w0.w
            + e1.x*w1.x + e1.y*w1.y + e1.z*w1.z + e1.w*w1.w;
  float ssa = e0.x*e0.x + e0.y*e0.y + e0.z*e0.z + e0.w*e0.w
            + e1.x*e1.x + e1.y*e1.y + e1.z*e1.z + e1.w*e1.w;
  float ssw = w0.x*w0.x + w0.y*w0.y + w0.z*w0.z + w0.w*w0.w
            + w1.x*w1.x + w1.y*w1.y + w1.z*w1.z + w1.w*w1.w;
  #pragma unroll
  for (int off = 32; off; off >>= 1) {
    dot += __shfl_xor(dot, off, 64);
    ssa += __shfl_xor(ssa, off, 64);
    ssw += __shfl_xor(ssw, off, 64);
  }
  const float inva = mm ? (1.0f / fmaxf(sqrtf(ssa), 1e-12f)) : 1.0f;
  float4 q0 = make_float4(e0.x*inva, e0.y*inva, e0.z*inva, e0.w*inva);
  float4 q1 = make_float4(e1.x*inva, e1.y*inva, e1.z*inva, e1.w*inva);
  *(uint2*)(Aq + (size_t)row * EMBD + lane * 8) = pack8_fp8(q0, q1);

  if (lane == 0) {
    lab32[row] = lab;
    float tv;
    if (mm) {
      float cosv = dot / (fmaxf(sqrtf(ssa), 1e-12f) * fmaxf(sqrtf(ssw), 1e-12f));
      float sinv = sqrtf(fmaxf(1.0f - cosv * cosv, 0.0f));
      float wmarg = cosv * COS_M - sinv * SIN_M;
      float nt = (cosv > THRESH) ? wmarg : (cosv - MM_C);
      tv = 64.0f * nt;
    } else {
      tv = dot;
    }
    tsc[row] = tv;
  }
  if (blockIdx.x == 0 && tid == 0) out[0] = 0.0f;
}

// ---------------------------------------------------------------- prep W -> fp8
__global__ __launch_bounds__(256) void prep_w_k(
    const float* __restrict__ weight, const float* __restrict__ fcw,
    const int* __restrict__ epoch, unsigned char* __restrict__ Wq) {
  const bool mm = (*epoch > 30);
  const float* W = mm ? weight : fcw;
  const int w = threadIdx.x >> 6, lane = threadIdx.x & 63;
  const int row = blockIdx.x * 4 + w;            // 0..100095
  unsigned char* dst = Wq + (size_t)row * EMBD + lane * 8;
  if (row >= NC) {
    *(uint2*)dst = make_uint2(0u, 0u);
    return;
  }
  const float* src = W + (size_t)row * EMBD + lane * 8;
  float4 a = *(const float4*)src;
  float4 b = *(const float4*)(src + 4);
  float ss = a.x*a.x + a.y*a.y + a.z*a.z + a.w*a.w
           + b.x*b.x + b.y*b.y + b.z*b.z + b.w*b.w;
  #pragma unroll
  for (int off = 32; off; off >>= 1) ss += __shfl_xor(ss, off, 64);
  const float inv = mm ? (1.0f / fmaxf(sqrtf(ss), 1e-12f)) : 1.0f;
  float4 qa = make_float4(a.x*inv, a.y*inv, a.z*inv, a.w*inv);
  float4 qb = make_float4(b.x*inv, b.y*inv, b.z*inv, b.w*inv);
  *(uint2*)dst = pack8_fp8(qa, qb);
}

// ---------------------------------------------------------------- fused fp8 GEMM + chunk-softmax
// block = 128x128 tile; 4 waves; wave w owns rows [w*32, w*32+32) x 128 cols.
// MFMA: mfma_scale_f32_16x16x128_f8f6f4 (e4m3/e4m3, unit scales).
// LDS tiles swizzled: row m's 16B-chunk j stored at chunk j^(m&7) (conflict-free
// frag reads); swizzle applied at the GLOBAL address so global_load_lds's
// contiguous lane->LDS mapping is preserved. Identical A/B k-order => any
// HW k-permutation cancels in the dot product.
__global__ __launch_bounds__(256, 2) void gemm_fused_k(
    const unsigned char* __restrict__ Aq, const unsigned char* __restrict__ Wq,
    const float* __restrict__ tsc, const int* __restrict__ lab32,
    const int* __restrict__ epoch, float2* __restrict__ partials) {
  const int t = blockIdx.x & 31, gblk = blockIdx.x >> 5;
  const int bn = gblk * 8 + (t & 7);     // XCD swizzle: 4 bm's of one bn land
  const int bm = t >> 3;                 // 8 dispatch-ids apart (same XCD)
  if (bn >= NCH) return;

  const bool mm = (*epoch > 30);
  const float scale = mm ? 64.0f : 1.0f;

  __shared__ unsigned char As[128 * 128];   // 16 KB
  __shared__ unsigned char Bs[128 * 128];   // 16 KB
  __shared__ float tscS[128];
  __shared__ int   labS[128];

  const int tid  = threadIdx.x;
  const int lane = tid & 63;
  const int w    = tid >> 6;
  const int m0   = bm * 128;
  const int n0   = bn * 128;

  if (tid < 128) { tscS[tid] = tsc[m0 + tid]; labS[tid] = lab32[m0 + tid]; }

  floatx4 acc[2][8];
  #pragma unroll
  for (int i = 0; i < 2; i++)
    #pragma unroll
    for (int j = 0; j < 8; j++) acc[i][j] = (floatx4){0.f, 0.f, 0.f, 0.f};

  // staging: each 1KB seg = 8 rows x 128B. wave w stages segs for its rows
  // (A rows w*32..w*32+31) and B rows w*32..w*32+31.
  const int rseg = lane >> 3;                       // row within seg
  const int swz  = ((lane & 7) ^ rseg) * 16;        // swizzled 16B chunk
  const unsigned char* gA[4];
  const unsigned char* gB[4];
  #pragma unroll
  for (int s = 0; s < 4; s++) {
    gA[s] = Aq + (size_t)(m0 + w * 32 + s * 8 + rseg) * EMBD + swz;
    gB[s] = Wq + (size_t)(n0 + w * 32 + s * 8 + rseg) * EMBD + swz;
  }

  const int rsel = lane & 15;
  const int g2   = (lane >> 4) * 2;                 // chunk pair base
  const int c0   = (g2 ^ (rsel & 7)) * 16;          // swizzled chunk offsets
  const int c1   = ((g2 + 1) ^ (rsel & 7)) * 16;

  for (int kt = 0; kt < 4; ++kt) {
    #pragma unroll
    for (int s = 0; s < 4; s++) {
      GLOAD16(gA[s] + kt * 128, &As[(w * 32 + s * 8) * 128]);
      GLOAD16(gB[s] + kt * 128, &Bs[(w * 32 + s * 8) * 128]);
    }
    __syncthreads();

    intx8 af[2], bv[8];
    #pragma unroll
    for (int mi = 0; mi < 2; mi++) {
      const int base = (w * 32 + mi * 16 + rsel) * 128;
      intx4 lo = *(const intx4*)&As[base + c0];
      intx4 hi = *(const intx4*)&As[base + c1];
      af[mi] = __builtin_shufflevector(lo, hi, 0, 1, 2, 3, 4, 5, 6, 7);
    }
    #pragma unroll
    for (int ni = 0; ni < 8; ni++) {
      const int base = (ni * 16 + rsel) * 128;
      intx4 lo = *(const intx4*)&Bs[base + c0];
      intx4 hi = *(const intx4*)&Bs[base + c1];
      bv[ni] = __builtin_shufflevector(lo, hi, 0, 1, 2, 3, 4, 5, 6, 7);
    }
    #pragma unroll
    for (int mi = 0; mi < 2; mi++)
      #pragma unroll
      for (int ni = 0; ni < 8; ni++)
        acc[mi][ni] = __builtin_amdgcn_mfma_scale_f32_16x16x128_f8f6f4(
            af[mi], bv[ni], acc[mi][ni], 0, 0,
            0, 0x7f7f7f7f, 0, 0x7f7f7f7f);
    __syncthreads();
  }

  // epilogue: C/D layout col = lane&15, row = (lane>>4)*4 + r (shape-determined)
  const int colq = lane & 15;
  #pragma unroll
  for (int mi = 0; mi < 2; mi++) {
    #pragma unroll
    for (int r = 0; r < 4; r++) {
      const int rl = w * 32 + mi * 16 + (lane >> 4) * 4 + r;
      const int lab = labS[rl];
      const float tv = tscS[rl];
      float v[8];
      #pragma unroll
      for (int ni = 0; ni < 8; ni++) {
        const int cg = n0 + ni * 16 + colq;
        float x = acc[mi][ni][r] * scale;
        if (cg >= NC) x = -1e30f;
        else if (cg == lab) x = tv;
        v[ni] = x;
      }
      float mx = v[0];
      #pragma unroll
      for (int ni = 1; ni < 8; ni++) mx = fmaxf(mx, v[ni]);
      #pragma unroll
      for (int off = 1; off < 16; off <<= 1) mx = fmaxf(mx, __shfl_xor(mx, off, 64));
      float s = 0.0f;
      #pragma unroll
      for (int ni = 0; ni < 8; ni++) s += __expf(v[ni] - mx);
      #pragma unroll
      for (int off = 1; off < 16; off <<= 1) s += __shfl_xor(s, off, 64);
      if (colq == 0)
        partials[(size_t)(m0 + rl) * NCH + bn] = make_float2(mx, s);
    }
  }
}

// ---------------------------------------------------------------- per-row logsumexp + atomic mean
__global__ __launch_bounds__(256) void rowmerge_k(
    const float2* __restrict__ partials, const float* __restrict__ tsc,
    float* __restrict__ out) {
  const int row = blockIdx.x;    // 512
  const int tid = threadIdx.x;   // 256
  float M = -1e30f, S = 0.0f;
  for (int j = tid; j < NCH; j += 256) {
    const float2 p = partials[(size_t)row * NCH + j];
    if (p.x > M) { S = S * __expf(M - p.x) + p.y; M = p.x; }
    else         { S += p.y * __expf(p.x - M); }
  }
  __shared__ float sm[256], sv[256];
  sm[tid] = M; sv[tid] = S;
  __syncthreads();
  for (int st = 128; st > 0; st >>= 1) {
    if (tid < st) {
      const float m2 = sm[tid + st], s2 = sv[tid + st];
      const float m1 = sm[tid],      s1 = sv[tid];
      const float Mn = fmaxf(m1, m2);
      sv[tid] = s1 * __expf(m1 - Mn) + s2 * __expf(m2 - Mn);
      sm[tid] = Mn;
    }
    __syncthreads();
  }
  if (tid == 0) {
    const float loss = (sm[0] + __logf(sv[0])) - tsc[row];
    atomicAdd(out, loss * (1.0f / 512.0f));
  }
}

// ----------------------------------------------------------------
extern "C" void kernel_launch(void* const* d_in, const int* in_sizes, int n_in,
                              void* d_out, int out_size, void* d_ws, size_t ws_size,
                              hipStream_t stream) {
  const float* emb    = (const float*)d_in[0];
  const float* weight = (const float*)d_in[1];
  const float* fcw    = (const float*)d_in[2];
  const int*   labels = (const int*)d_in[3];
  const int*   epoch  = (const int*)d_in[4];
  float* out = (float*)d_out;

  char* ws = (char*)d_ws;
  size_t off = 0;
  unsigned char* Aq = (unsigned char*)(ws + off); off += (size_t)BATCH * EMBD;   // 256 KB
  unsigned char* Wq = (unsigned char*)(ws + off); off += (size_t)NCP * EMBD;     // ~51 MB
  float* tsc       = (float*)(ws + off); off += BATCH * 4;
  int* lab32       = (int*)(ws + off);   off += BATCH * 4;
  float2* partials = (float2*)(ws + off); off += (size_t)BATCH * NCH * 8;        // ~3.2 MB

  prep_small_k<<<BATCH / 4, 256, 0, stream>>>(emb, weight, fcw, labels, epoch,
                                              Aq, tsc, lab32, out);
  prep_w_k<<<NCP / 4, 256, 0, stream>>>(weight, fcw, epoch, Wq);
  gemm_fused_k<<<98 * 32, 256, 0, stream>>>(Aq, Wq, tsc, lab32, epoch, partials);
  rowmerge_k<<<BATCH, 256, 0, stream>>>(partials, tsc, out);
}